// Round 3
// baseline (556.466 us; speedup 1.0000x reference)
//
#include <hip/hip_runtime.h>
#include <stdint.h>

typedef unsigned int uint;
typedef unsigned short ushort;
typedef unsigned char uchar;
typedef __attribute__((ext_vector_type(8))) short bf16x8;
typedef __attribute__((ext_vector_type(4))) float f32x4;

__device__ __forceinline__ ushort f2bf(float f) {
  uint u = __builtin_bit_cast(uint, f);
  return (ushort)((u + 0x7FFFu + ((u >> 16) & 1u)) >> 16);
}

// 8 mask bytes (nonzero == true) -> bf16x8 of 1.0/0.0 + packed u16 popcount.
__device__ __forceinline__ bf16x8 cvt8(uint lo, uint hi, uint& cacc) {
  uint x0 = __builtin_amdgcn_perm(0u, lo, 0x04010400u);
  uint x1 = __builtin_amdgcn_perm(0u, lo, 0x04030402u);
  uint x2 = __builtin_amdgcn_perm(0u, hi, 0x04010400u);
  uint x3 = __builtin_amdgcn_perm(0u, hi, 0x04030402u);
  uint n0 = ((x0 + 0x00FF00FFu) >> 8) & 0x00010001u;
  uint n1 = ((x1 + 0x00FF00FFu) >> 8) & 0x00010001u;
  uint n2 = ((x2 + 0x00FF00FFu) >> 8) & 0x00010001u;
  uint n3 = ((x3 + 0x00FF00FFu) >> 8) & 0x00010001u;
  cacc += n0 + n1 + n2 + n3;
  uint4 o;
  o.x = n0 * 0x3F80u; o.y = n1 * 0x3F80u;
  o.z = n2 * 0x3F80u; o.w = n3 * 0x3F80u;
  return __builtin_bit_cast(bf16x8, o);
}

__device__ __forceinline__ bf16x8 cvt8w(uint4 a, uint4 b, uint& cnt) {
  bf16x8 r;
  r[0] = a.x ? (short)0x3F80 : (short)0; cnt += (a.x != 0u);
  r[1] = a.y ? (short)0x3F80 : (short)0; cnt += (a.y != 0u);
  r[2] = a.z ? (short)0x3F80 : (short)0; cnt += (a.z != 0u);
  r[3] = a.w ? (short)0x3F80 : (short)0; cnt += (a.w != 0u);
  r[4] = b.x ? (short)0x3F80 : (short)0; cnt += (b.x != 0u);
  r[5] = b.y ? (short)0x3F80 : (short)0; cnt += (b.y != 0u);
  r[6] = b.z ? (short)0x3F80 : (short)0; cnt += (b.z != 0u);
  r[7] = b.w ? (short)0x3F80 : (short)0; cnt += (b.w != 0u);
  return r;
}

// ---------------------------------------------------------------------------
__global__ __launch_bounds__(256) void k_detect(
    const uint4* __restrict__ m, int* __restrict__ esz_out) {
  __shared__ int s_ok;
  if (threadIdx.x == 0) s_ok = 1;
  __syncthreads();
  int ok = 1;
#pragma unroll
  for (int i = 0; i < 16; ++i) {
    uint4 v = m[i * 256 + threadIdx.x];
    if (!(v.x <= 1u || v.x == 0x3F800000u)) ok = 0;
    if (!(v.y <= 1u || v.y == 0x3F800000u)) ok = 0;
    if (!(v.z <= 1u || v.z == 0x3F800000u)) ok = 0;
    if (!(v.w <= 1u || v.w == 0x3F800000u)) ok = 0;
  }
  if (!ok) atomicAnd(&s_ok, 0);
  __syncthreads();
  if (threadIdx.x == 0) *esz_out = s_ok ? 4 : 1;
}

// ---------------------------------------------------------------------------
__global__ __launch_bounds__(256) void k_prep(
    const float4* __restrict__ fin, ushort* __restrict__ fout,
    const float* __restrict__ We, const float* __restrict__ Ws,
    const float* __restrict__ Wm, const float* __restrict__ Wx,
    ushort* __restrict__ Te, ushort* __restrict__ Ts,
    ushort* __restrict__ Tm, ushort* __restrict__ Tx) {
  const int tid = blockIdx.x * 256 + threadIdx.x;
  for (int i = tid; i < 524288; i += 180224) {
    float4 v = fin[i];
    ushort4 o;
    o.x = f2bf(v.x); o.y = f2bf(v.y); o.z = f2bf(v.z); o.w = f2bf(v.w);
    *(ushort4*)&fout[(size_t)i * 4] = o;
  }
  int i = tid;
  if (i < 65536) { int n = i >> 7, k = i & 127; Te[i] = f2bf(We[k * 512 + n]); return; }
  i -= 65536;
  if (i < 49152) { int n = i / 384, k = i - n * 384; Ts[i] = f2bf(Ws[k * 128 + n]); return; }
  i -= 49152;
  if (i < 32768) { int n = i >> 8, k = i & 255; Tm[i] = f2bf(Wm[k * 128 + n]); return; }
  i -= 32768;
  if (i < 32768) { int n = i >> 8, k = i & 255; Tx[i] = f2bf(Wx[k * 128 + n]); return; }
}

// ---------------------------------------------------------------------------
// Encoder GEMM (unchanged from round 2).
__global__ __launch_bounds__(256) void k_enc(
    const ushort* __restrict__ featbf, const ushort* __restrict__ WTe,
    const float* __restrict__ bias, ushort* __restrict__ origin,
    ushort* __restrict__ eT0, ushort* __restrict__ eT1, ushort* __restrict__ eT2) {
  __shared__ ushort tr[128 * 64];
  const int t = threadIdx.x;
  const int gm0 = blockIdx.x * 64;
  const int y = blockIdx.y;
  const int lane = t & 63, wave = t >> 6;
  const int m0w = (wave >> 1) * 32, n0w = (wave & 1) * 64;
  const int quad = lane >> 4, lr = lane & 15;
  const ushort* a0p = featbf + (size_t)(gm0 + m0w + lr) * 128 + quad * 8;
  const ushort* a1p = a0p + 16 * 128;
  bf16x8 af0[4], af1[4];
#pragma unroll
  for (int kc = 0; kc < 4; ++kc) {
    af0[kc] = *(const bf16x8*)(a0p + kc * 32);
    af1[kc] = *(const bf16x8*)(a1p + kc * 32);
  }
  f32x4 acc[2][4] = {};
#pragma unroll
  for (int j = 0; j < 4; ++j) {
    const ushort* bp = WTe + (size_t)(y * 128 + n0w + j * 16 + lr) * 128 + quad * 8;
#pragma unroll
    for (int kc = 0; kc < 4; ++kc) {
      bf16x8 bv = *(const bf16x8*)(bp + kc * 32);
      acc[0][j] = __builtin_amdgcn_mfma_f32_16x16x32_bf16(af0[kc], bv, acc[0][j], 0, 0, 0);
      acc[1][j] = __builtin_amdgcn_mfma_f32_16x16x32_bf16(af1[kc], bv, acc[1][j], 0, 0, 0);
    }
  }
  if (y == 0) {
#pragma unroll
    for (int i = 0; i < 2; ++i)
#pragma unroll
      for (int j = 0; j < 4; ++j) {
        int n = n0w + j * 16 + lr;
        float bb = bias[n];
        int mb = gm0 + m0w + i * 16 + quad * 4;
#pragma unroll
        for (int r = 0; r < 4; ++r)
          origin[(size_t)(mb + r) * 128 + n] = f2bf(acc[i][j][r] + bb);
      }
  } else {
    ushort* eT = (y == 1) ? eT0 : (y == 2) ? eT1 : eT2;
#pragma unroll
    for (int i = 0; i < 2; ++i)
#pragma unroll
      for (int j = 0; j < 4; ++j) {
        int n = n0w + j * 16 + lr;
        float bb = bias[y * 128 + n];
        int m_lo = m0w + i * 16 + quad * 4;
        int chunk = m_lo >> 3;
        int byteo = n * 128 + ((chunk ^ (n & 7)) << 4) + (m_lo & 7) * 2;
        ushort4 o;
        o.x = f2bf(acc[i][j][0] + bb);
        o.y = f2bf(acc[i][j][1] + bb);
        o.z = f2bf(acc[i][j][2] + bb);
        o.w = f2bf(acc[i][j][3] + bb);
        *(ushort4*)((char*)tr + byteo) = o;
      }
    __syncthreads();
    const int n = t >> 1, half = t & 1;
    ushort* gp = eT + (size_t)n * 16384 + gm0 + half * 32;
#pragma unroll
    for (int cc = 0; cc < 4; ++cc) {
      int c = half * 4 + cc;
      uint4 v = *(const uint4*)((char*)tr + n * 128 + ((c ^ (n & 7)) << 4));
      *(uint4*)&gp[cc * 8] = v;
    }
  }
}

// ---------------------------------------------------------------------------
// Shared epilogue for the masked-mean kernels.
__device__ __forceinline__ void mm_epilogue(
    uint* degs, f32x4 acc[2][4], uint cacc0, uint cacc1, int esz,
    int m0w, int n0w, int quad, int lr, int wave,
    ushort* outp, size_t rowbase) {
  const int r0 = m0w + lr, r1 = m0w + 16 + lr;
  int c0, c1;
  if (esz == 1) {
    c0 = (int)((cacc0 & 0xFFFFu) + (cacc0 >> 16));
    c1 = (int)((cacc1 & 0xFFFFu) + (cacc1 >> 16));
  } else {
    c0 = (int)cacc0;
    c1 = (int)cacc1;
  }
  c0 += __shfl_xor(c0, 16); c0 += __shfl_xor(c0, 32);
  c1 += __shfl_xor(c1, 16); c1 += __shfl_xor(c1, 32);
  if ((wave & 1) == 0 && quad == 0) { degs[r0] = (uint)c0; degs[r1] = (uint)c1; }
  __syncthreads();
#pragma unroll
  for (int i = 0; i < 2; ++i)
#pragma unroll
    for (int r = 0; r < 4; ++r) {
      int ml = m0w + i * 16 + quad * 4 + r;
      uint d = degs[ml];
      float inv = 1.0f / (float)(d > 0u ? d : 1u);
#pragma unroll
      for (int j = 0; j < 4; ++j) {
        int n = n0w + j * 16 + lr;
        outp[(rowbase + ml) * 128 + n] = f2bf(acc[i][j][r] * inv);
      }
    }
}

// esz==4 fallback body (direct loads; not the bench's live path).
__device__ __forceinline__ void mm_esz4(
    const void* mask, const ushort* eT, size_t rowbase, int b,
    int m0w, int n0w, int quad, int lr,
    f32x4 acc[2][4], uint& cacc0, uint& cacc1) {
  const int r0 = m0w + lr, r1 = m0w + 16 + lr;
  const ushort* bp0 = eT + (size_t)(n0w + lr) * 16384 + (size_t)b * 2048 + quad * 8;
  const ushort* bp1 = bp0 + 16 * 16384;
  const ushort* bp2 = bp0 + 32 * 16384;
  const ushort* bp3 = bp0 + 48 * 16384;
  const uint* ma = (const uint*)mask + (rowbase + r0) * 2048 + quad * 8;
  const uint* mb = (const uint*)mask + (rowbase + r1) * 2048 + quad * 8;
  for (int k0 = 0; k0 < 2048; k0 += 64) {
#pragma unroll
    for (int kc = 0; kc < 2; ++kc) {
      uint4 wa0 = *(const uint4*)(ma + k0 + kc * 32);
      uint4 wa1 = *(const uint4*)(ma + k0 + kc * 32 + 4);
      uint4 wb0 = *(const uint4*)(mb + k0 + kc * 32);
      uint4 wb1 = *(const uint4*)(mb + k0 + kc * 32 + 4);
      bf16x8 bv0 = *(const bf16x8*)(bp0 + k0 + kc * 32);
      bf16x8 bv1 = *(const bf16x8*)(bp1 + k0 + kc * 32);
      bf16x8 bv2 = *(const bf16x8*)(bp2 + k0 + kc * 32);
      bf16x8 bv3 = *(const bf16x8*)(bp3 + k0 + kc * 32);
      bf16x8 a0 = cvt8w(wa0, wa1, cacc0);
      bf16x8 a1 = cvt8w(wb0, wb1, cacc1);
      acc[0][0] = __builtin_amdgcn_mfma_f32_16x16x32_bf16(a0, bv0, acc[0][0], 0, 0, 0);
      acc[1][0] = __builtin_amdgcn_mfma_f32_16x16x32_bf16(a1, bv0, acc[1][0], 0, 0, 0);
      acc[0][1] = __builtin_amdgcn_mfma_f32_16x16x32_bf16(a0, bv1, acc[0][1], 0, 0, 0);
      acc[1][1] = __builtin_amdgcn_mfma_f32_16x16x32_bf16(a1, bv1, acc[1][1], 0, 0, 0);
      acc[0][2] = __builtin_amdgcn_mfma_f32_16x16x32_bf16(a0, bv2, acc[0][2], 0, 0, 0);
      acc[1][2] = __builtin_amdgcn_mfma_f32_16x16x32_bf16(a1, bv2, acc[1][2], 0, 0, 0);
      acc[0][3] = __builtin_amdgcn_mfma_f32_16x16x32_bf16(a0, bv3, acc[0][3], 0, 0, 0);
      acc[1][3] = __builtin_amdgcn_mfma_f32_16x16x32_bf16(a1, bv3, acc[1][3], 0, 0, 0);
    }
  }
}

// ---------------------------------------------------------------------------
// VARIANT A: all-LDS staging, 3 buffers (depth-2-phases), counted vmcnt(10),
// raw barriers, XOR-swizzled LDS with inverse-swizzled gload_lds sources.
// Panels 0..11. LDS = 3*(16KB B + 4KB A) = 60 KB -> 2 blocks/CU.
__global__ __launch_bounds__(256, 2) void k_mmA(
    const void* __restrict__ mp, const void* __restrict__ ms,
    const void* __restrict__ mt,
    const ushort* __restrict__ eT0, const ushort* __restrict__ eT1,
    const ushort* __restrict__ eT2,
    ushort* __restrict__ P, ushort* __restrict__ S, ushort* __restrict__ T,
    const int* __restrict__ esz_p) {
  __shared__ __align__(16) char smem[61440];  // B:3*16384 @0, A:3*4096 @49152
  const int t = threadIdx.x;
  const int mtile = blockIdx.x;
  const int panel = blockIdx.y;  // 0..11
  const int b = panel / 3, mid = panel - b * 3;
  const void* mask = (mid == 0) ? mp : (mid == 1) ? ms : mt;
  const ushort* eT = (mid == 0) ? eT0 : (mid == 1) ? eT1 : eT2;
  ushort* outp = (mid == 0) ? P : (mid == 1) ? S : T;
  const int esz = *esz_p;
  const size_t rowbase = (size_t)b * 2048 + mtile * 64;
  const int lane = t & 63, wave = t >> 6;
  const int m0w = (wave >> 1) * 32, n0w = (wave & 1) * 64;
  const int quad = lane >> 4, lr = lane & 15;
  f32x4 acc[2][4] = {};
  uint cacc0 = 0, cacc1 = 0;

  if (esz == 1) {
    // staging source addresses (inverse-swizzled)
    const int r0B = wave * 32 + (lane >> 3);
    const ushort* gB = eT + (size_t)r0B * 16384 + (size_t)b * 2048 +
                       ((lane & 7) ^ (r0B & 7)) * 8;
    const int r0A = wave * 16 + (lane >> 2);
    const uchar* gA = (const uchar*)mask + (size_t)(rowbase + r0A) * 2048 +
                      (((lane & 3) ^ (r0A & 3)) << 4);

#define STG(BUF, PH)                                                          \
  {                                                                           \
    _Pragma("unroll") for (int ii = 0; ii < 4; ++ii)                          \
        __builtin_amdgcn_global_load_lds(                                     \
            (const __attribute__((address_space(1))) uint*)(gB +              \
                (size_t)ii * 8 * 16384 + (PH) * 64),                          \
            (__attribute__((address_space(3))) uint*)(smem + (BUF) * 16384 +  \
                wave * 4096 + ii * 1024 + lane * 16),                         \
            16, 0, 0);                                                        \
    __builtin_amdgcn_global_load_lds(                                         \
        (const __attribute__((address_space(1))) uint*)(gA + (PH) * 64),      \
        (__attribute__((address_space(3))) uint*)(smem + 49152 +              \
            (BUF) * 4096 + wave * 1024 + lane * 16),                          \
        16, 0, 0);                                                            \
  }

#define CPT(BUF)                                                              \
  {                                                                           \
    const char* Bb = smem + (BUF) * 16384;                                    \
    const char* Ab = smem + 49152 + (BUF) * 4096;                             \
    _Pragma("unroll") for (int kc = 0; kc < 2; ++kc) {                        \
      const int ach = (((kc << 1) + (quad >> 1)) ^ (lr & 3)) << 4;            \
      uint2 va0 = *(const uint2*)(Ab + (m0w + lr) * 64 + ach + (quad & 1) * 8); \
      uint2 va1 = *(const uint2*)(Ab + (m0w + 16 + lr) * 64 + ach + (quad & 1) * 8); \
      const int bch = (((kc << 2) + quad) ^ (lr & 7)) << 4;                   \
      bf16x8 b0 = *(const bf16x8*)(Bb + (n0w + lr) * 128 + bch);              \
      bf16x8 b1 = *(const bf16x8*)(Bb + (n0w + 16 + lr) * 128 + bch);         \
      bf16x8 b2 = *(const bf16x8*)(Bb + (n0w + 32 + lr) * 128 + bch);         \
      bf16x8 b3 = *(const bf16x8*)(Bb + (n0w + 48 + lr) * 128 + bch);         \
      bf16x8 a0 = cvt8(va0.x, va0.y, cacc0);                                  \
      bf16x8 a1 = cvt8(va1.x, va1.y, cacc1);                                  \
      __builtin_amdgcn_s_setprio(1);                                          \
      acc[0][0] = __builtin_amdgcn_mfma_f32_16x16x32_bf16(a0, b0, acc[0][0], 0, 0, 0); \
      acc[1][0] = __builtin_amdgcn_mfma_f32_16x16x32_bf16(a1, b0, acc[1][0], 0, 0, 0); \
      acc[0][1] = __builtin_amdgcn_mfma_f32_16x16x32_bf16(a0, b1, acc[0][1], 0, 0, 0); \
      acc[1][1] = __builtin_amdgcn_mfma_f32_16x16x32_bf16(a1, b1, acc[1][1], 0, 0, 0); \
      acc[0][2] = __builtin_amdgcn_mfma_f32_16x16x32_bf16(a0, b2, acc[0][2], 0, 0, 0); \
      acc[1][2] = __builtin_amdgcn_mfma_f32_16x16x32_bf16(a1, b2, acc[1][2], 0, 0, 0); \
      acc[0][3] = __builtin_amdgcn_mfma_f32_16x16x32_bf16(a0, b3, acc[0][3], 0, 0, 0); \
      acc[1][3] = __builtin_amdgcn_mfma_f32_16x16x32_bf16(a1, b3, acc[1][3], 0, 0, 0); \
      __builtin_amdgcn_s_setprio(0);                                          \
    }                                                                         \
  }

#define ITER(BUF, VM)                                                         \
  asm volatile("s_waitcnt vmcnt(" #VM ")" ::: "memory");                      \
  __builtin_amdgcn_s_barrier();                                               \
  __builtin_amdgcn_sched_barrier(0);                                          \
  CPT(BUF);                                                                   \
  asm volatile("" ::: "memory");                                              \
  __builtin_amdgcn_s_barrier();                                               \
  asm volatile("" ::: "memory");

    STG(0, 0)
    STG(1, 1)
    STG(2, 2)
    for (int ph = 0; ph < 27; ph += 3) {
      ITER(0, 10) STG(0, ph + 3)
      ITER(1, 10) STG(1, ph + 4)
      ITER(2, 10) STG(2, ph + 5)
    }
    ITER(0, 10) STG(0, 30)
    ITER(1, 10) STG(1, 31)
    ITER(2, 10)
    ITER(0, 5)
    ITER(1, 0)
#undef ITER
#undef CPT
#undef STG
  } else {
    mm_esz4(mask, eT, rowbase, b, m0w, n0w, quad, lr, acc, cacc0, cacc1);
  }
  __syncthreads();
  mm_epilogue((uint*)smem, acc, cacc0, cacc1, esz, m0w, n0w, quad, lr, wave,
              outp, rowbase);
}

// ---------------------------------------------------------------------------
// VARIANT B: barrier-free register pipeline; both operands double-buffered in
// registers, 4 independent waves/block. Panels 12..23.
__global__ __launch_bounds__(256, 3) void k_mmB(
    const void* __restrict__ mp, const void* __restrict__ ms,
    const void* __restrict__ mt,
    const ushort* __restrict__ eT0, const ushort* __restrict__ eT1,
    const ushort* __restrict__ eT2,
    ushort* __restrict__ P, ushort* __restrict__ S, ushort* __restrict__ T,
    const int* __restrict__ esz_p) {
  __shared__ uint degs[64];
  const int t = threadIdx.x;
  const int mtile = blockIdx.x;
  const int panel = 12 + blockIdx.y;  // 12..23
  const int b = panel / 3, mid = panel - b * 3;
  const void* mask = (mid == 0) ? mp : (mid == 1) ? ms : mt;
  const ushort* eT = (mid == 0) ? eT0 : (mid == 1) ? eT1 : eT2;
  ushort* outp = (mid == 0) ? P : (mid == 1) ? S : T;
  const int esz = *esz_p;
  const size_t rowbase = (size_t)b * 2048 + mtile * 64;
  const int lane = t & 63, wave = t >> 6;
  const int m0w = (wave >> 1) * 32, n0w = (wave & 1) * 64;
  const int quad = lane >> 4, lr = lane & 15;
  f32x4 acc[2][4] = {};
  uint cacc0 = 0, cacc1 = 0;

  if (esz == 1) {
    const int r0 = m0w + lr, r1 = m0w + 16 + lr;
    const uchar* ma = (const uchar*)mask + (rowbase + r0) * 2048 + quad * 8;
    const uchar* mb = (const uchar*)mask + (rowbase + r1) * 2048 + quad * 8;
    const ushort* bp0 = eT + (size_t)(n0w + lr) * 16384 + (size_t)b * 2048 + quad * 8;
    const ushort* bp1 = bp0 + 16 * 16384;
    const ushort* bp2 = bp0 + 32 * 16384;
    const ushort* bp3 = bp0 + 48 * 16384;
    uint2 a00, a01, a10, a11;  // cur
    uint2 c00, c01, c10, c11;  // nxt
    bf16x8 B0[8], B1[8];

#define LDA0(K)                                                               \
  { a00 = *(const uint2*)(ma + (K)); a01 = *(const uint2*)(ma + (K) + 32);    \
    a10 = *(const uint2*)(mb + (K)); a11 = *(const uint2*)(mb + (K) + 32); }
#define LDA1(K)                                                               \
  { c00 = *(const uint2*)(ma + (K)); c01 = *(const uint2*)(ma + (K) + 32);    \
    c10 = *(const uint2*)(mb + (K)); c11 = *(const uint2*)(mb + (K) + 32); }
#define LDB(ARR, K)                                                           \
  { ARR[0] = *(const bf16x8*)(bp0 + (K));      ARR[1] = *(const bf16x8*)(bp1 + (K)); \
    ARR[2] = *(const bf16x8*)(bp2 + (K));      ARR[3] = *(const bf16x8*)(bp3 + (K)); \
    ARR[4] = *(const bf16x8*)(bp0 + (K) + 32); ARR[5] = *(const bf16x8*)(bp1 + (K) + 32); \
    ARR[6] = *(const bf16x8*)(bp2 + (K) + 32); ARR[7] = *(const bf16x8*)(bp3 + (K) + 32); }
#define CPTR(A00, A01, A10, A11, BB)                                          \
  {                                                                           \
    bf16x8 a0 = cvt8((A00).x, (A00).y, cacc0);                                \
    bf16x8 a1 = cvt8((A10).x, (A10).y, cacc1);                                \
    acc[0][0] = __builtin_amdgcn_mfma_f32_16x16x32_bf16(a0, BB[0], acc[0][0], 0, 0, 0); \
    acc[1][0] = __builtin_amdgcn_mfma_f32_16x16x32_bf16(a1, BB[0], acc[1][0], 0, 0, 0); \
    acc[0][1] = __builtin_amdgcn_mfma_f32_16x16x32_bf16(a0, BB[1], acc[0][1], 0, 0, 0); \
    acc[1][1] = __builtin_amdgcn_mfma_f32_16x16x32_bf16(a1, BB[1], acc[1][1], 0, 0, 0); \
    acc[0][2] = __builtin_amdgcn_mfma_f32_16x16x32_bf16(a0, BB[2], acc[0][2], 0, 0, 0); \
    acc[1][2] = __builtin_amdgcn_mfma_f32_16x16x32_bf16(a1, BB[2], acc[1][2], 0, 0, 0); \
    acc[0][3] = __builtin_amdgcn_mfma_f32_16x16x32_bf16(a0, BB[3], acc[0][3], 0, 0, 0); \
    acc[1][3] = __builtin_amdgcn_mfma_f32_16x16x32_bf16(a1, BB[3], acc[1][3], 0, 0, 0); \
    bf16x8 a0h = cvt8((A01).x, (A01).y, cacc0);                               \
    bf16x8 a1h = cvt8((A11).x, (A11).y, cacc1);                               \
    acc[0][0] = __builtin_amdgcn_mfma_f32_16x16x32_bf16(a0h, BB[4], acc[0][0], 0, 0, 0); \
    acc[1][0] = __builtin_amdgcn_mfma_f32_16x16x32_bf16(a1h, BB[4], acc[1][0], 0, 0, 0); \
    acc[0][1] = __builtin_amdgcn_mfma_f32_16x16x32_bf16(a0h, BB[5], acc[0][1], 0, 0, 0); \
    acc[1][1] = __builtin_amdgcn_mfma_f32_16x16x32_bf16(a1h, BB[5], acc[1][1], 0, 0, 0); \
    acc[0][2] = __builtin_amdgcn_mfma_f32_16x16x32_bf16(a0h, BB[6], acc[0][2], 0, 0, 0); \
    acc[1][2] = __builtin_amdgcn_mfma_f32_16x16x32_bf16(a1h, BB[6], acc[1][2], 0, 0, 0); \
    acc[0][3] = __builtin_amdgcn_mfma_f32_16x16x32_bf16(a0h, BB[7], acc[0][3], 0, 0, 0); \
    acc[1][3] = __builtin_amdgcn_mfma_f32_16x16x32_bf16(a1h, BB[7], acc[1][3], 0, 0, 0); \
  }

    LDA0(0)  LDB(B0, 0)
    LDA1(64) LDB(B1, 64)
    for (int k0 = 0; k0 < 1792; k0 += 128) {
      CPTR(a00, a01, a10, a11, B0)
      LDA0(k0 + 128) LDB(B0, k0 + 128)
      CPTR(c00, c01, c10, c11, B1)
      LDA1(k0 + 192) LDB(B1, k0 + 192)
    }
    CPTR(a00, a01, a10, a11, B0)
    LDA0(1920) LDB(B0, 1920)
    CPTR(c00, c01, c10, c11, B1)
    LDA1(1984) LDB(B1, 1984)
    CPTR(a00, a01, a10, a11, B0)
    CPTR(c00, c01, c10, c11, B1)
#undef CPTR
#undef LDB
#undef LDA1
#undef LDA0
  } else {
    mm_esz4(mask, eT, rowbase, b, m0w, n0w, quad, lr, acc, cacc0, cacc1);
  }
  mm_epilogue(degs, acc, cacc0, cacc1, esz, m0w, n0w, quad, lr, wave,
              outp, rowbase);
}

// ---------------------------------------------------------------------------
__device__ __forceinline__ void gemm_body(
    const ushort* __restrict__ A0, const ushort* __restrict__ A1,
    const ushort* __restrict__ A2, const ushort* __restrict__ Bsrc,
    int bstride, int K, const float* __restrict__ bias,
    void* __restrict__ out, int out_f32, int gm0, int t) {
  const int lane = t & 63, wave = t >> 6;
  const int m0w = (wave >> 1) * 32, n0w = (wave & 1) * 64;
  const int quad = lane >> 4, lr = lane & 15;
  const ushort* bbase = Bsrc + (size_t)(n0w + lr) * bstride + quad * 8;
  f32x4 acc[2][4] = {};
  for (int k0 = 0; k0 < K; k0 += 64) {
    const int seg = k0 >> 7;
    const ushort* Ap = (seg == 0) ? A0 : (seg == 1) ? A1 : A2;
    const int ko = k0 & 127;
    const ushort* a0p = Ap + (size_t)(gm0 + m0w + lr) * 128 + ko + quad * 8;
    const ushort* a1p = a0p + 16 * 128;
#pragma unroll
    for (int kc = 0; kc < 2; ++kc) {
      bf16x8 av0 = *(const bf16x8*)(a0p + kc * 32);
      bf16x8 av1 = *(const bf16x8*)(a1p + kc * 32);
      bf16x8 b0 = *(const bf16x8*)(bbase + k0 + kc * 32);
      bf16x8 b1 = *(const bf16x8*)(bbase + (size_t)16 * bstride + k0 + kc * 32);
      bf16x8 b2 = *(const bf16x8*)(bbase + (size_t)32 * bstride + k0 + kc * 32);
      bf16x8 b3 = *(const bf16x8*)(bbase + (size_t)48 * bstride + k0 + kc * 32);
      acc[0][0] = __builtin_amdgcn_mfma_f32_16x16x32_bf16(av0, b0, acc[0][0], 0, 0, 0);
      acc[1][0] = __builtin_amdgcn_mfma_f32_16x16x32_bf16(av1, b0, acc[1][0], 0, 0, 0);
      acc[0][1] = __builtin_amdgcn_mfma_f32_16x16x32_bf16(av0, b1, acc[0][1], 0, 0, 0);
      acc[1][1] = __builtin_amdgcn_mfma_f32_16x16x32_bf16(av1, b1, acc[1][1], 0, 0, 0);
      acc[0][2] = __builtin_amdgcn_mfma_f32_16x16x32_bf16(av0, b2, acc[0][2], 0, 0, 0);
      acc[1][2] = __builtin_amdgcn_mfma_f32_16x16x32_bf16(av1, b2, acc[1][2], 0, 0, 0);
      acc[0][3] = __builtin_amdgcn_mfma_f32_16x16x32_bf16(av0, b3, acc[0][3], 0, 0, 0);
      acc[1][3] = __builtin_amdgcn_mfma_f32_16x16x32_bf16(av1, b3, acc[1][3], 0, 0, 0);
    }
  }
#pragma unroll
  for (int i = 0; i < 2; ++i)
#pragma unroll
    for (int j = 0; j < 4; ++j) {
      const int n = n0w + j * 16 + lr;
      const float bb = bias[n];
      const int mb = gm0 + m0w + i * 16 + quad * 4;
      if (out_f32) {
#pragma unroll
        for (int r = 0; r < 4; ++r)
          ((float*)out)[(size_t)(mb + r) * 128 + n] = acc[i][j][r] + bb;
      } else {
#pragma unroll
        for (int r = 0; r < 4; ++r)
          ((ushort*)out)[(size_t)(mb + r) * 128 + n] = f2bf(acc[i][j][r] + bb);
      }
    }
}

__global__ __launch_bounds__(256) void k_xy(
    const ushort* __restrict__ P, const ushort* __restrict__ origin,
    const ushort* __restrict__ S, const ushort* __restrict__ T,
    const ushort* __restrict__ WTs, const ushort* __restrict__ WTm,
    const float* __restrict__ bs, const float* __restrict__ bm,
    ushort* __restrict__ X, ushort* __restrict__ Y) {
  const int gm0 = blockIdx.x * 64;
  if (blockIdx.y == 0)
    gemm_body(P, origin, S, WTs, 384, 384, bs, X, 0, gm0, threadIdx.x);
  else
    gemm_body(origin, T, nullptr, WTm, 256, 256, bm, Y, 0, gm0, threadIdx.x);
}

__global__ __launch_bounds__(256) void k_mix(
    const ushort* __restrict__ X, const ushort* __restrict__ Y,
    const ushort* __restrict__ WTx, const float* __restrict__ bx,
    float* __restrict__ out) {
  gemm_body(X, Y, nullptr, WTx, 256, 256, bx, out, 1, blockIdx.x * 64, threadIdx.x);
}

// ---------------------------------------------------------------------------
extern "C" void kernel_launch(void* const* d_in, const int* in_sizes, int n_in,
                              void* d_out, int out_size, void* d_ws,
                              size_t ws_size, hipStream_t stream) {
  const float* features = (const float*)d_in[0];
  const void* pred = d_in[1];
  const void* succ = d_in[2];
  const void* same = d_in[3];
  const float* W_enc = (const float*)d_in[4];
  const float* b_enc = (const float*)d_in[5];
  const float* W_space = (const float*)d_in[6];
  const float* b_space = (const float*)d_in[7];
  const float* W_same = (const float*)d_in[8];
  const float* b_same = (const float*)d_in[9];
  const float* W_mix = (const float*)d_in[10];
  const float* b_mix = (const float*)d_in[11];

  const size_t M = 16384;
  ushort* w = (ushort*)d_ws;
  ushort* feat_bf = w;  w += M * 128;
  ushort* WT_enc = w;   w += 512 * 128;
  ushort* WT_space = w; w += 128 * 384;
  ushort* WT_same = w;  w += 128 * 256;
  ushort* WT_mix = w;   w += 128 * 256;
  ushort* origin = w;   w += M * 128;
  ushort* eT0 = w;      w += M * 128;
  ushort* eT1 = w;      w += M * 128;
  ushort* eT2 = w;      w += M * 128;
  ushort* P = w;        w += M * 128;
  ushort* S = w;        w += M * 128;
  ushort* T = w;        w += M * 128;
  ushort* X = w;        w += M * 128;
  ushort* Y = w;        w += M * 128;
  int* esz = (int*)w;

  k_detect<<<1, 256, 0, stream>>>((const uint4*)pred, esz);
  k_prep<<<704, 256, 0, stream>>>((const float4*)features, feat_bf,
                                  W_enc, W_space, W_same, W_mix,
                                  WT_enc, WT_space, WT_same, WT_mix);
  k_enc<<<dim3(256, 4), 256, 0, stream>>>(feat_bf, WT_enc, b_enc,
                                          origin, eT0, eT1, eT2);
  k_mmA<<<dim3(32, 12), 256, 0, stream>>>(pred, succ, same, eT0, eT1, eT2,
                                          P, S, T, esz);
  k_mmB<<<dim3(32, 12), 256, 0, stream>>>(pred, succ, same, eT0, eT1, eT2,
                                          P, S, T, esz);
  k_xy<<<dim3(256, 2), 256, 0, stream>>>(P, origin, S, T, WT_space, WT_same,
                                         b_space, b_same, X, Y);
  k_mix<<<256, 256, 0, stream>>>(X, Y, WT_mix, b_mix, (float*)d_out);
}

// Round 5
// 490.407 us; speedup vs baseline: 1.1347x; 1.1347x over previous
//
#include <hip/hip_runtime.h>
#include <stdint.h>

typedef unsigned int uint;
typedef unsigned short ushort;
typedef unsigned char uchar;
typedef __attribute__((ext_vector_type(8))) short bf16x8;
typedef __attribute__((ext_vector_type(4))) float f32x4;

__device__ __forceinline__ ushort f2bf(float f) {
  uint u = __builtin_bit_cast(uint, f);
  return (ushort)((u + 0x7FFFu + ((u >> 16) & 1u)) >> 16);
}

// 4 bytes -> 4 nonzero bits (bit i = byte i != 0)
__device__ __forceinline__ uint nz4(uint x) {
  uint y = (x & 0x7F7F7F7Fu) + 0x7F7F7F7Fu;
  uint z = (y | x) & 0x80808080u;
  return ((z >> 7) & 1u) | ((z >> 14) & 2u) | ((z >> 21) & 4u) | ((z >> 28) & 8u);
}
// 4 dwords -> 4 nonzero bits
__device__ __forceinline__ uint nzd4(uint4 v) {
  return (uint)(v.x != 0u) | ((uint)(v.y != 0u) << 1) |
         ((uint)(v.z != 0u) << 2) | ((uint)(v.w != 0u) << 3);
}
// 8 bits -> bf16x8 of 1.0/0.0
__device__ __forceinline__ bf16x8 bits2bf(uint byte) {
  bf16x8 r;
#pragma unroll
  for (int e = 0; e < 8; ++e)
    r[e] = (short)(ushort)(((byte >> e) & 1u) ? 0x3F80u : 0u);
  return r;
}

// ---------------------------------------------------------------------------
__global__ __launch_bounds__(256) void k_detect(
    const uint4* __restrict__ m, int* __restrict__ esz_out) {
  __shared__ int s_ok;
  if (threadIdx.x == 0) s_ok = 1;
  __syncthreads();
  int ok = 1;
#pragma unroll
  for (int i = 0; i < 16; ++i) {
    uint4 v = m[i * 256 + threadIdx.x];
    if (!(v.x <= 1u || v.x == 0x3F800000u)) ok = 0;
    if (!(v.y <= 1u || v.y == 0x3F800000u)) ok = 0;
    if (!(v.z <= 1u || v.z == 0x3F800000u)) ok = 0;
    if (!(v.w <= 1u || v.w == 0x3F800000u)) ok = 0;
  }
  if (!ok) atomicAnd(&s_ok, 0);
  __syncthreads();
  if (threadIdx.x == 0) *esz_out = s_ok ? 4 : 1;
}

// ---------------------------------------------------------------------------
__global__ __launch_bounds__(256) void k_prep(
    const float4* __restrict__ fin, ushort* __restrict__ fout,
    const float* __restrict__ We, const float* __restrict__ Ws,
    const float* __restrict__ Wm, const float* __restrict__ Wx,
    ushort* __restrict__ Te, ushort* __restrict__ Ts,
    ushort* __restrict__ Tm, ushort* __restrict__ Tx) {
  const int tid = blockIdx.x * 256 + threadIdx.x;
  for (int i = tid; i < 524288; i += 180224) {
    float4 v = fin[i];
    ushort4 o;
    o.x = f2bf(v.x); o.y = f2bf(v.y); o.z = f2bf(v.z); o.w = f2bf(v.w);
    *(ushort4*)&fout[(size_t)i * 4] = o;
  }
  int i = tid;
  if (i < 65536) { int n = i >> 7, k = i & 127; Te[i] = f2bf(We[k * 512 + n]); return; }
  i -= 65536;
  if (i < 49152) { int n = i / 384, k = i - n * 384; Ts[i] = f2bf(Ws[k * 128 + n]); return; }
  i -= 49152;
  if (i < 32768) { int n = i >> 8, k = i & 255; Tm[i] = f2bf(Wm[k * 128 + n]); return; }
  i -= 32768;
  if (i < 32768) { int n = i >> 8, k = i & 255; Tx[i] = f2bf(Wx[k * 128 + n]); return; }
}

// ---------------------------------------------------------------------------
// Mask bit-pack + degree precompute. Output tiled to match k_mm's A-tiles:
// pk[mid][b][mtile][kstep][64 rows][8 B]; invdeg[mid][b][2048] = 1/max(deg,1).
// Fully-coalesced streaming read of the byte masks.
__global__ __launch_bounds__(256) void k_maskpack(
    const void* __restrict__ mp, const void* __restrict__ ms,
    const void* __restrict__ mt, uchar* __restrict__ pk,
    float* __restrict__ invdeg, const int* __restrict__ esz_p) {
  const int t = threadIdx.x;
  const int rg = blockIdx.x;          // row-group: 8 rows
  const int y = blockIdx.y;           // 0..23
  const int mid = y >> 3, b = y & 7;
  const void* mask = (mid == 0) ? mp : (mid == 1) ? ms : mt;
  const int esz = *esz_p;
  const int rl = t >> 5, seg = t & 31;  // seg == kstep
  const int r = rg * 8 + rl;            // row in batch
  uint lo, hi;
  if (esz == 1) {
    const uint4* p = (const uint4*)((const uchar*)mask +
                                    ((size_t)b * 2048 + r) * 2048 + seg * 64);
    uint4 v0 = p[0], v1 = p[1], v2 = p[2], v3 = p[3];
    uint q0 = nz4(v0.x) | (nz4(v0.y) << 4) | (nz4(v0.z) << 8) | (nz4(v0.w) << 12);
    uint q1 = nz4(v1.x) | (nz4(v1.y) << 4) | (nz4(v1.z) << 8) | (nz4(v1.w) << 12);
    uint q2 = nz4(v2.x) | (nz4(v2.y) << 4) | (nz4(v2.z) << 8) | (nz4(v2.w) << 12);
    uint q3 = nz4(v3.x) | (nz4(v3.y) << 4) | (nz4(v3.z) << 8) | (nz4(v3.w) << 12);
    lo = q0 | (q1 << 16);
    hi = q2 | (q3 << 16);
  } else {
    const uint4* p = (const uint4*)mask + ((size_t)b * 2048 + r) * 512 + seg * 16;
    uint q[4];
#pragma unroll
    for (int g = 0; g < 4; ++g) {
      uint4 w0 = p[g * 4 + 0], w1 = p[g * 4 + 1];
      uint4 w2 = p[g * 4 + 2], w3 = p[g * 4 + 3];
      q[g] = nzd4(w0) | (nzd4(w1) << 4) | (nzd4(w2) << 8) | (nzd4(w3) << 12);
    }
    lo = q[0] | (q[1] << 16);
    hi = q[2] | (q[3] << 16);
  }
  int cnt = __popc(lo) + __popc(hi);
#pragma unroll
  for (int o = 1; o < 32; o <<= 1) cnt += __shfl_xor(cnt, o);
  if (seg == 0)
    invdeg[((size_t)mid * 8 + b) * 2048 + r] =
        1.0f / (float)(cnt > 0 ? cnt : 1);
  const int mtile = r >> 6, rowin = r & 63;
  uint2 w2v; w2v.x = lo; w2v.y = hi;
  *(uint2*)(pk + (((((size_t)(mid * 8 + b)) * 32 + mtile) * 32 + seg) * 64 +
                  rowin) * 8) = w2v;
}

// ---------------------------------------------------------------------------
// Encoder GEMM. y==0 -> origin row-major. y>0 -> eTt tiled layout:
// eTt[b][kstep][128 n][8 slots][16B], slot s holds m-chunk (s ^ (n&7))
// (the LDS-image swizzle baked into memory so k_mm can gload_lds linearly).
__global__ __launch_bounds__(256) void k_enc(
    const ushort* __restrict__ featbf, const ushort* __restrict__ WTe,
    const float* __restrict__ bias, ushort* __restrict__ origin,
    ushort* __restrict__ eTt0, ushort* __restrict__ eTt1, ushort* __restrict__ eTt2) {
  __shared__ ushort tr[128 * 64];  // the 16KB swizzled tile image
  const int t = threadIdx.x;
  const int gm0 = blockIdx.x * 64;
  const int y = blockIdx.y;
  const int lane = t & 63, wave = t >> 6;
  const int m0w = (wave >> 1) * 32, n0w = (wave & 1) * 64;
  const int quad = lane >> 4, lr = lane & 15;
  const ushort* a0p = featbf + (size_t)(gm0 + m0w + lr) * 128 + quad * 8;
  const ushort* a1p = a0p + 16 * 128;
  bf16x8 af0[4], af1[4];
#pragma unroll
  for (int kc = 0; kc < 4; ++kc) {
    af0[kc] = *(const bf16x8*)(a0p + kc * 32);
    af1[kc] = *(const bf16x8*)(a1p + kc * 32);
  }
  f32x4 acc[2][4] = {};
#pragma unroll
  for (int j = 0; j < 4; ++j) {
    const ushort* bp = WTe + (size_t)(y * 128 + n0w + j * 16 + lr) * 128 + quad * 8;
#pragma unroll
    for (int kc = 0; kc < 4; ++kc) {
      bf16x8 bv = *(const bf16x8*)(bp + kc * 32);
      acc[0][j] = __builtin_amdgcn_mfma_f32_16x16x32_bf16(af0[kc], bv, acc[0][j], 0, 0, 0);
      acc[1][j] = __builtin_amdgcn_mfma_f32_16x16x32_bf16(af1[kc], bv, acc[1][j], 0, 0, 0);
    }
  }
  if (y == 0) {
#pragma unroll
    for (int i = 0; i < 2; ++i)
#pragma unroll
      for (int j = 0; j < 4; ++j) {
        int n = n0w + j * 16 + lr;
        float bb = bias[n];
        int mb = gm0 + m0w + i * 16 + quad * 4;
#pragma unroll
        for (int r = 0; r < 4; ++r)
          origin[(size_t)(mb + r) * 128 + n] = f2bf(acc[i][j][r] + bb);
      }
  } else {
#pragma unroll
    for (int i = 0; i < 2; ++i)
#pragma unroll
      for (int j = 0; j < 4; ++j) {
        int n = n0w + j * 16 + lr;
        float bb = bias[y * 128 + n];
        int m_lo = m0w + i * 16 + quad * 4;
        int chunk = m_lo >> 3;
        int byteo = n * 128 + ((chunk ^ (n & 7)) << 4) + (m_lo & 7) * 2;
        ushort4 o;
        o.x = f2bf(acc[i][j][0] + bb);
        o.y = f2bf(acc[i][j][1] + bb);
        o.z = f2bf(acc[i][j][2] + bb);
        o.w = f2bf(acc[i][j][3] + bb);
        *(ushort4*)((char*)tr + byteo) = o;
      }
    __syncthreads();
    // linear 16KB copy of the tile image to eTt[b][kstep]
    ushort* eT = (y == 1) ? eTt0 : (y == 2) ? eTt1 : eTt2;
    const int bb_ = blockIdx.x >> 5, kstep = blockIdx.x & 31;
    uint4* dst = (uint4*)(eT + ((size_t)(bb_ * 32 + kstep)) * 8192);
    const uint4* src = (const uint4*)tr;
#pragma unroll
    for (int ii = 0; ii < 4; ++ii) dst[ii * 256 + t] = src[ii * 256 + t];
  }
}

// ---------------------------------------------------------------------------
// Masked mean on packed bits + tiled eT. Per step: B = one contiguous 16KB
// tile (L2-shared by 32 sibling blocks) via gload_lds double-buffer with
// counted vmcnt(4); A = bit-tile staged once in prologue. No strides, no
// popcount. Grid flat 768, XCD-pinned panels.
__global__ __launch_bounds__(256, 3) void k_mm(
    const uchar* __restrict__ pk, const float* __restrict__ invdeg,
    const ushort* __restrict__ B0p, const ushort* __restrict__ B1p,
    const ushort* __restrict__ B2p,
    ushort* __restrict__ P, ushort* __restrict__ S, ushort* __restrict__ T) {
  __shared__ __align__(16) char smem[49152];  // A bits @0 (16K), B bufs @16K/32K
  const int t = threadIdx.x;
  const int g = blockIdx.x;
  const int X = g & 7, seq = g >> 3;
  const int pl = seq >> 5, mtile = seq & 31;
  const int panel = pl * 8 + X;
  const int b = panel / 3, mid = panel - b * 3;
  const ushort* Bt = (mid == 0) ? B0p : (mid == 1) ? B1p : B2p;
  ushort* outp = (mid == 0) ? P : (mid == 1) ? S : T;
  const uchar* pkT = pk + ((((size_t)(mid * 8 + b)) * 32 + mtile) * 32) * 512;
  const uchar* BtT = (const uchar*)Bt + ((size_t)b * 32) * 16384;
  const int lane = t & 63, wave = t >> 6;
  const int m0w = (wave >> 1) * 32, n0w = (wave & 1) * 64;
  const int quad = lane >> 4, lr = lane & 15;
  f32x4 acc[2][4] = {};

#define STG_A()                                                               \
  {                                                                           \
    _Pragma("unroll") for (int ii = 0; ii < 4; ++ii)                          \
        __builtin_amdgcn_global_load_lds(                                     \
            (const __attribute__((address_space(1))) uint*)(pkT +             \
                wave * 4096 + ii * 1024 + lane * 16),                         \
            (__attribute__((address_space(3))) uint*)(smem + wave * 4096 +    \
                ii * 1024 + lane * 16),                                       \
            16, 0, 0);                                                        \
  }
#define STG_B(BUF, STEP)                                                      \
  {                                                                           \
    _Pragma("unroll") for (int ii = 0; ii < 4; ++ii)                          \
        __builtin_amdgcn_global_load_lds(                                     \
            (const __attribute__((address_space(1))) uint*)(BtT +             \
                (size_t)(STEP) * 16384 + wave * 4096 + ii * 1024 + lane * 16),\
            (__attribute__((address_space(3))) uint*)(smem + 16384 +          \
                (BUF) * 16384 + wave * 4096 + ii * 1024 + lane * 16),         \
            16, 0, 0);                                                        \
  }
#define CPT(SS, BUF)                                                          \
  {                                                                           \
    const char* Ab = smem;                                                    \
    const char* Bb = smem + 16384 + (BUF) * 16384;                            \
    uint2 wa = *(const uint2*)(Ab + (SS) * 512 + (m0w + lr) * 8);             \
    uint2 wb = *(const uint2*)(Ab + (SS) * 512 + (m0w + 16 + lr) * 8);        \
    _Pragma("unroll") for (int kc = 0; kc < 2; ++kc) {                        \
      uint wax = kc ? wa.y : wa.x;                                            \
      uint wbx = kc ? wb.y : wb.x;                                            \
      bf16x8 a0 = bits2bf((wax >> (quad * 8)) & 0xFFu);                       \
      bf16x8 a1 = bits2bf((wbx >> (quad * 8)) & 0xFFu);                       \
      const int sl = (((kc * 4 + quad) ^ (lr & 7)) << 4);                     \
      bf16x8 b0 = *(const bf16x8*)(Bb + (n0w + lr) * 128 + sl);               \
      bf16x8 b1 = *(const bf16x8*)(Bb + (n0w + 16 + lr) * 128 + sl);          \
      bf16x8 b2 = *(const bf16x8*)(Bb + (n0w + 32 + lr) * 128 + sl);          \
      bf16x8 b3 = *(const bf16x8*)(Bb + (n0w + 48 + lr) * 128 + sl);          \
      __builtin_amdgcn_s_setprio(1);                                          \
      acc[0][0] = __builtin_amdgcn_mfma_f32_16x16x32_bf16(a0, b0, acc[0][0], 0, 0, 0); \
      acc[1][0] = __builtin_amdgcn_mfma_f32_16x16x32_bf16(a1, b0, acc[1][0], 0, 0, 0); \
      acc[0][1] = __builtin_amdgcn_mfma_f32_16x16x32_bf16(a0, b1, acc[0][1], 0, 0, 0); \
      acc[1][1] = __builtin_amdgcn_mfma_f32_16x16x32_bf16(a1, b1, acc[1][1], 0, 0, 0); \
      acc[0][2] = __builtin_amdgcn_mfma_f32_16x16x32_bf16(a0, b2, acc[0][2], 0, 0, 0); \
      acc[1][2] = __builtin_amdgcn_mfma_f32_16x16x32_bf16(a1, b2, acc[1][2], 0, 0, 0); \
      acc[0][3] = __builtin_amdgcn_mfma_f32_16x16x32_bf16(a0, b3, acc[0][3], 0, 0, 0); \
      acc[1][3] = __builtin_amdgcn_mfma_f32_16x16x32_bf16(a1, b3, acc[1][3], 0, 0, 0); \
      __builtin_amdgcn_s_setprio(0);                                          \
    }                                                                         \
  }

  STG_A()
  STG_B(0, 0)
  STG_B(1, 1)
  for (int s = 0; s < 32; ++s) {
    if (s < 31) asm volatile("s_waitcnt vmcnt(4)" ::: "memory");
    else        asm volatile("s_waitcnt vmcnt(0)" ::: "memory");
    __builtin_amdgcn_s_barrier();
    __builtin_amdgcn_sched_barrier(0);
    CPT(s, s & 1)
    asm volatile("" ::: "memory");
    __builtin_amdgcn_s_barrier();
    if (s < 30) STG_B(s & 1, s + 2)
  }
  __builtin_amdgcn_sched_barrier(0);
#undef CPT
#undef STG_B
#undef STG_A

  const size_t rowbase = (size_t)b * 2048 + mtile * 64;
  const float* inv = invdeg + ((size_t)(mid * 8 + b)) * 2048 + mtile * 64;
#pragma unroll
  for (int i = 0; i < 2; ++i)
#pragma unroll
    for (int r = 0; r < 4; ++r) {
      int ml = m0w + i * 16 + quad * 4 + r;
      float iv = inv[ml];
#pragma unroll
      for (int j = 0; j < 4; ++j) {
        int n = n0w + j * 16 + lr;
        outp[(rowbase + ml) * 128 + n] = f2bf(acc[i][j][r] * iv);
      }
    }
}

// ---------------------------------------------------------------------------
__device__ __forceinline__ void gemm_body(
    const ushort* __restrict__ A0, const ushort* __restrict__ A1,
    const ushort* __restrict__ A2, const ushort* __restrict__ Bsrc,
    int bstride, int K, const float* __restrict__ bias,
    void* __restrict__ out, int out_f32, int gm0, int t) {
  const int lane = t & 63, wave = t >> 6;
  const int m0w = (wave >> 1) * 32, n0w = (wave & 1) * 64;
  const int quad = lane >> 4, lr = lane & 15;
  const ushort* bbase = Bsrc + (size_t)(n0w + lr) * bstride + quad * 8;
  f32x4 acc[2][4] = {};
  for (int k0 = 0; k0 < K; k0 += 64) {
    const int seg = k0 >> 7;
    const ushort* Ap = (seg == 0) ? A0 : (seg == 1) ? A1 : A2;
    const int ko = k0 & 127;
    const ushort* a0p = Ap + (size_t)(gm0 + m0w + lr) * 128 + ko + quad * 8;
    const ushort* a1p = a0p + 16 * 128;
#pragma unroll
    for (int kc = 0; kc < 2; ++kc) {
      bf16x8 av0 = *(const bf16x8*)(a0p + kc * 32);
      bf16x8 av1 = *(const bf16x8*)(a1p + kc * 32);
      bf16x8 b0 = *(const bf16x8*)(bbase + k0 + kc * 32);
      bf16x8 b1 = *(const bf16x8*)(bbase + (size_t)16 * bstride + k0 + kc * 32);
      bf16x8 b2 = *(const bf16x8*)(bbase + (size_t)32 * bstride + k0 + kc * 32);
      bf16x8 b3 = *(const bf16x8*)(bbase + (size_t)48 * bstride + k0 + kc * 32);
      acc[0][0] = __builtin_amdgcn_mfma_f32_16x16x32_bf16(av0, b0, acc[0][0], 0, 0, 0);
      acc[1][0] = __builtin_amdgcn_mfma_f32_16x16x32_bf16(av1, b0, acc[1][0], 0, 0, 0);
      acc[0][1] = __builtin_amdgcn_mfma_f32_16x16x32_bf16(av0, b1, acc[0][1], 0, 0, 0);
      acc[1][1] = __builtin_amdgcn_mfma_f32_16x16x32_bf16(av1, b1, acc[1][1], 0, 0, 0);
      acc[0][2] = __builtin_amdgcn_mfma_f32_16x16x32_bf16(av0, b2, acc[0][2], 0, 0, 0);
      acc[1][2] = __builtin_amdgcn_mfma_f32_16x16x32_bf16(av1, b2, acc[1][2], 0, 0, 0);
      acc[0][3] = __builtin_amdgcn_mfma_f32_16x16x32_bf16(av0, b3, acc[0][3], 0, 0, 0);
      acc[1][3] = __builtin_amdgcn_mfma_f32_16x16x32_bf16(av1, b3, acc[1][3], 0, 0, 0);
    }
  }
#pragma unroll
  for (int i = 0; i < 2; ++i)
#pragma unroll
    for (int j = 0; j < 4; ++j) {
      const int n = n0w + j * 16 + lr;
      const float bb = bias[n];
      const int mb = gm0 + m0w + i * 16 + quad * 4;
      if (out_f32) {
#pragma unroll
        for (int r = 0; r < 4; ++r)
          ((float*)out)[(size_t)(mb + r) * 128 + n] = acc[i][j][r] + bb;
      } else {
#pragma unroll
        for (int r = 0; r < 4; ++r)
          ((ushort*)out)[(size_t)(mb + r) * 128 + n] = f2bf(acc[i][j][r] + bb);
      }
    }
}

__global__ __launch_bounds__(256) void k_xy(
    const ushort* __restrict__ P, const ushort* __restrict__ origin,
    const ushort* __restrict__ S, const ushort* __restrict__ T,
    const ushort* __restrict__ WTs, const ushort* __restrict__ WTm,
    const float* __restrict__ bs, const float* __restrict__ bm,
    ushort* __restrict__ X, ushort* __restrict__ Y) {
  const int gm0 = blockIdx.x * 64;
  if (blockIdx.y == 0)
    gemm_body(P, origin, S, WTs, 384, 384, bs, X, 0, gm0, threadIdx.x);
  else
    gemm_body(origin, T, nullptr, WTm, 256, 256, bm, Y, 0, gm0, threadIdx.x);
}

__global__ __launch_bounds__(256) void k_mix(
    const ushort* __restrict__ X, const ushort* __restrict__ Y,
    const ushort* __restrict__ WTx, const float* __restrict__ bx,
    float* __restrict__ out) {
  gemm_body(X, Y, nullptr, WTx, 256, 256, bx, out, 1, blockIdx.x * 64, threadIdx.x);
}

// ---------------------------------------------------------------------------
extern "C" void kernel_launch(void* const* d_in, const int* in_sizes, int n_in,
                              void* d_out, int out_size, void* d_ws,
                              size_t ws_size, hipStream_t stream) {
  const float* features = (const float*)d_in[0];
  const void* pred = d_in[1];
  const void* succ = d_in[2];
  const void* same = d_in[3];
  const float* W_enc = (const float*)d_in[4];
  const float* b_enc = (const float*)d_in[5];
  const float* W_space = (const float*)d_in[6];
  const float* b_space = (const float*)d_in[7];
  const float* W_same = (const float*)d_in[8];
  const float* b_same = (const float*)d_in[9];
  const float* W_mix = (const float*)d_in[10];
  const float* b_mix = (const float*)d_in[11];

  const size_t M = 16384;
  ushort* w = (ushort*)d_ws;
  ushort* feat_bf = w;  w += M * 128;
  ushort* WT_enc = w;   w += 512 * 128;
  ushort* WT_space = w; w += 128 * 384;
  ushort* WT_same = w;  w += 128 * 256;
  ushort* WT_mix = w;   w += 128 * 256;
  ushort* origin = w;   w += M * 128;
  ushort* eTt0 = w;     w += M * 128;
  ushort* eTt1 = w;     w += M * 128;
  ushort* eTt2 = w;     w += M * 128;
  ushort* P = w;        w += M * 128;
  ushort* S = w;        w += M * 128;
  ushort* T = w;        w += M * 128;
  // pk needs 3*8*2048*2048 bits = 12,582,912 B = 6,291,456 ushorts.
  // X and Y alias the pk region: pk dies after k_mm; X/Y are born at k_xy.
  uchar* pk = (uchar*)w;
  ushort* X = w;
  ushort* Y = w + M * 128;
  w += 6291456;
  float* invdeg = (float*)w;  w += 98304;  // 3*8*2048 f32 = 196,608 B
  int* esz = (int*)w;

  k_detect<<<1, 256, 0, stream>>>((const uint4*)pred, esz);
  k_prep<<<704, 256, 0, stream>>>((const float4*)features, feat_bf,
                                  W_enc, W_space, W_same, W_mix,
                                  WT_enc, WT_space, WT_same, WT_mix);
  k_maskpack<<<dim3(256, 24), 256, 0, stream>>>(pred, succ, same, pk, invdeg, esz);
  k_enc<<<dim3(256, 4), 256, 0, stream>>>(feat_bf, WT_enc, b_enc,
                                          origin, eTt0, eTt1, eTt2);
  k_mm<<<768, 256, 0, stream>>>(pk, invdeg, eTt0, eTt1, eTt2, P, S, T);
  k_xy<<<dim3(256, 2), 256, 0, stream>>>(P, origin, S, T, WT_space, WT_same,
                                         b_space, b_same, X, Y);
  k_mix<<<256, 256, 0, stream>>>(X, Y, WT_mix, b_mix, (float*)d_out);
}

// Round 6
// 473.517 us; speedup vs baseline: 1.1752x; 1.0357x over previous
//
#include <hip/hip_runtime.h>
#include <stdint.h>

typedef unsigned int uint;
typedef unsigned short ushort;
typedef unsigned char uchar;
typedef __attribute__((ext_vector_type(8))) short bf16x8;
typedef __attribute__((ext_vector_type(4))) float f32x4;

__device__ __forceinline__ ushort f2bf(float f) {
  uint u = __builtin_bit_cast(uint, f);
  return (ushort)((u + 0x7FFFu + ((u >> 16) & 1u)) >> 16);
}

// 4 bytes -> 4 nonzero bits (bit i = byte i != 0)
__device__ __forceinline__ uint nz4(uint x) {
  uint y = (x & 0x7F7F7F7Fu) + 0x7F7F7F7Fu;
  uint z = (y | x) & 0x80808080u;
  return ((z >> 7) & 1u) | ((z >> 14) & 2u) | ((z >> 21) & 4u) | ((z >> 28) & 8u);
}
// 8 bits -> bf16x8 of 1.0/0.0
__device__ __forceinline__ bf16x8 bits2bf(uint byte) {
  bf16x8 r;
#pragma unroll
  for (int e = 0; e < 8; ++e)
    r[e] = (short)(ushort)(((byte >> e) & 1u) ? 0x3F80u : 0u);
  return r;
}

// ---------------------------------------------------------------------------
// Mask element width detection (4-byte int/float vs 1-byte bool).
__global__ __launch_bounds__(256) void k_detect(
    const uint4* __restrict__ m, int* __restrict__ esz_out) {
  __shared__ int s_ok;
  if (threadIdx.x == 0) s_ok = 1;
  __syncthreads();
  int ok = 1;
#pragma unroll
  for (int i = 0; i < 16; ++i) {
    uint4 v = m[i * 256 + threadIdx.x];
    if (!(v.x <= 1u || v.x == 0x3F800000u)) ok = 0;
    if (!(v.y <= 1u || v.y == 0x3F800000u)) ok = 0;
    if (!(v.z <= 1u || v.z == 0x3F800000u)) ok = 0;
    if (!(v.w <= 1u || v.w == 0x3F800000u)) ok = 0;
  }
  if (!ok) atomicAnd(&s_ok, 0);
  __syncthreads();
  if (threadIdx.x == 0) *esz_out = s_ok ? 4 : 1;
}

// ---------------------------------------------------------------------------
// Fused front: mask bit-pack + degree (blocks 0..1535) and weight transpose
// (blocks 1536..2239). pk tile layout (16KB per (panel,mtile)):
// [64 rows][32 kslots][8B], slot stored at (kstep ^ (row&31)).
// esz==4 path: ballot packer — lane l reads element s*64+l (256B/instr wave-
// coalesced), __ballot(v!=0) IS the packed word; lanes 0..31 store one row's
// 256B image in a single coalesced store.
__global__ __launch_bounds__(256) void k_front(
    const void* __restrict__ mp, const void* __restrict__ ms,
    const void* __restrict__ mt, uchar* __restrict__ pk,
    float* __restrict__ invdeg, const int* __restrict__ esz_p,
    const float* __restrict__ We, const float* __restrict__ Ws,
    const float* __restrict__ Wm, const float* __restrict__ Wx,
    ushort* __restrict__ Te, ushort* __restrict__ Ts,
    ushort* __restrict__ Tm, ushort* __restrict__ Tx) {
  const int t = threadIdx.x;
  if (blockIdx.x >= 1536) {  // ---- weight transpose part ----
    int i = (blockIdx.x - 1536) * 256 + t;
    if (i < 65536) { int n = i >> 7, k = i & 127; Te[i] = f2bf(We[k * 512 + n]); return; }
    i -= 65536;
    if (i < 49152) { int n = i / 384, k = i - n * 384; Ts[i] = f2bf(Ws[k * 128 + n]); return; }
    i -= 49152;
    if (i < 32768) { int n = i >> 8, k = i & 255; Tm[i] = f2bf(Wm[k * 128 + n]); return; }
    i -= 32768;
    if (i < 32768) { int n = i >> 8, k = i & 255; Tx[i] = f2bf(Wx[k * 128 + n]); return; }
    return;
  }
  const int esz = *esz_p;
  const int lane = t & 63, wave = t >> 6;
  if (esz == 4) {
    const int wgid = blockIdx.x * 4 + wave;  // 0..6143
    for (int rr = wgid; rr < 49152; rr += 6144) {
      const int mid = rr >> 14, rem = rr & 16383;
      const int b = rem >> 11, rrow = rem & 2047;
      const uint* src =
          (const uint*)((mid == 0) ? mp : (mid == 1) ? ms : mt) +
          ((size_t)b * 2048 + rrow) * 2048;
      unsigned long long kept = 0ull;
#pragma unroll
      for (int s = 0; s < 32; ++s) {
        uint v = src[s * 64 + lane];
        unsigned long long bal = __ballot(v != 0u);
        if (lane == s) kept = bal;
      }
      int cnt = __popcll(kept);
#pragma unroll
      for (int o = 1; o < 64; o <<= 1) cnt += __shfl_xor(cnt, o);
      const int mtile = rrow >> 6, rowin = rrow & 63;
      uchar* tb = pk + ((((size_t)(mid * 8 + b)) * 32 + mtile)) * 16384;
      if (lane < 32) {
        uint2 kv;
        kv.x = (uint)kept;
        kv.y = (uint)(kept >> 32);
        *(uint2*)(tb + rowin * 256 + ((lane ^ (rowin & 31)) << 3)) = kv;
      }
      if (lane == 0)
        invdeg[((size_t)mid * 8 + b) * 2048 + rrow] =
            1.0f / (float)(cnt > 0 ? cnt : 1);
    }
  } else {  // esz==1 (byte masks): 4 work-units per thread
    const int gtid = blockIdx.x * 256 + t;
    for (int k = 0; k < 4; ++k) {
      const int u = gtid + k * 393216;
      const int row = u >> 5, seg = u & 31;
      const int mid = row >> 14, b = (row >> 11) & 7, rrow = row & 2047;
      const void* mask = (mid == 0) ? mp : (mid == 1) ? ms : mt;
      const uint4* p = (const uint4*)((const uchar*)mask +
                                      ((size_t)b * 2048 + rrow) * 2048 + seg * 64);
      uint4 v0 = p[0], v1 = p[1], v2 = p[2], v3 = p[3];
      uint q0 = nz4(v0.x) | (nz4(v0.y) << 4) | (nz4(v0.z) << 8) | (nz4(v0.w) << 12);
      uint q1 = nz4(v1.x) | (nz4(v1.y) << 4) | (nz4(v1.z) << 8) | (nz4(v1.w) << 12);
      uint q2 = nz4(v2.x) | (nz4(v2.y) << 4) | (nz4(v2.z) << 8) | (nz4(v2.w) << 12);
      uint q3 = nz4(v3.x) | (nz4(v3.y) << 4) | (nz4(v3.z) << 8) | (nz4(v3.w) << 12);
      uint lo = q0 | (q1 << 16);
      uint hi = q2 | (q3 << 16);
      int cnt = __popc(lo) + __popc(hi);
#pragma unroll
      for (int o = 1; o < 32; o <<= 1) cnt += __shfl_xor(cnt, o);
      if (seg == 0)
        invdeg[((size_t)mid * 8 + b) * 2048 + rrow] =
            1.0f / (float)(cnt > 0 ? cnt : 1);
      const int mtile = rrow >> 6, rowin = rrow & 63;
      uint2 w2v; w2v.x = lo; w2v.y = hi;
      *(uint2*)(pk + ((((size_t)(mid * 8 + b)) * 32 + mtile)) * 16384 +
                rowin * 256 + ((seg ^ (rowin & 31)) << 3)) = w2v;
    }
  }
}

// ---------------------------------------------------------------------------
// Encoder GEMM; A = raw f32 features converted inline (no feat_bf pass).
// y==0 -> origin row-major. y>0 -> eTt tiled: eTt[b][kstep][128n][8 slots][16B],
// slot s holds m-chunk (s ^ (n&7)).
__global__ __launch_bounds__(256) void k_enc(
    const float* __restrict__ features, const ushort* __restrict__ WTe,
    const float* __restrict__ bias, ushort* __restrict__ origin,
    ushort* __restrict__ eTt0, ushort* __restrict__ eTt1, ushort* __restrict__ eTt2) {
  __shared__ ushort tr[128 * 64];  // 16KB swizzled tile image
  const int t = threadIdx.x;
  const int gm0 = blockIdx.x * 64;
  const int y = blockIdx.y;
  const int lane = t & 63, wave = t >> 6;
  const int m0w = (wave >> 1) * 32, n0w = (wave & 1) * 64;
  const int quad = lane >> 4, lr = lane & 15;
  const float* a0f = features + (size_t)(gm0 + m0w + lr) * 128 + quad * 8;
  const float* a1f = a0f + 16 * 128;
  bf16x8 af0[4], af1[4];
#pragma unroll
  for (int kc = 0; kc < 4; ++kc) {
    float4 x0 = *(const float4*)(a0f + kc * 32);
    float4 x1 = *(const float4*)(a0f + kc * 32 + 4);
    float4 y0 = *(const float4*)(a1f + kc * 32);
    float4 y1 = *(const float4*)(a1f + kc * 32 + 4);
    bf16x8 a, b;
    a[0] = (short)f2bf(x0.x); a[1] = (short)f2bf(x0.y);
    a[2] = (short)f2bf(x0.z); a[3] = (short)f2bf(x0.w);
    a[4] = (short)f2bf(x1.x); a[5] = (short)f2bf(x1.y);
    a[6] = (short)f2bf(x1.z); a[7] = (short)f2bf(x1.w);
    b[0] = (short)f2bf(y0.x); b[1] = (short)f2bf(y0.y);
    b[2] = (short)f2bf(y0.z); b[3] = (short)f2bf(y0.w);
    b[4] = (short)f2bf(y1.x); b[5] = (short)f2bf(y1.y);
    b[6] = (short)f2bf(y1.z); b[7] = (short)f2bf(y1.w);
    af0[kc] = a; af1[kc] = b;
  }
  f32x4 acc[2][4] = {};
#pragma unroll
  for (int j = 0; j < 4; ++j) {
    const ushort* bp = WTe + (size_t)(y * 128 + n0w + j * 16 + lr) * 128 + quad * 8;
#pragma unroll
    for (int kc = 0; kc < 4; ++kc) {
      bf16x8 bv = *(const bf16x8*)(bp + kc * 32);
      acc[0][j] = __builtin_amdgcn_mfma_f32_16x16x32_bf16(af0[kc], bv, acc[0][j], 0, 0, 0);
      acc[1][j] = __builtin_amdgcn_mfma_f32_16x16x32_bf16(af1[kc], bv, acc[1][j], 0, 0, 0);
    }
  }
  if (y == 0) {
#pragma unroll
    for (int i = 0; i < 2; ++i)
#pragma unroll
      for (int j = 0; j < 4; ++j) {
        int n = n0w + j * 16 + lr;
        float bb = bias[n];
        int mb = gm0 + m0w + i * 16 + quad * 4;
#pragma unroll
        for (int r = 0; r < 4; ++r)
          origin[(size_t)(mb + r) * 128 + n] = f2bf(acc[i][j][r] + bb);
      }
  } else {
#pragma unroll
    for (int i = 0; i < 2; ++i)
#pragma unroll
      for (int j = 0; j < 4; ++j) {
        int n = n0w + j * 16 + lr;
        float bb = bias[y * 128 + n];
        int m_lo = m0w + i * 16 + quad * 4;
        int chunk = m_lo >> 3;
        int byteo = n * 128 + ((chunk ^ (n & 7)) << 4) + (m_lo & 7) * 2;
        ushort4 o;
        o.x = f2bf(acc[i][j][0] + bb);
        o.y = f2bf(acc[i][j][1] + bb);
        o.z = f2bf(acc[i][j][2] + bb);
        o.w = f2bf(acc[i][j][3] + bb);
        *(ushort4*)((char*)tr + byteo) = o;
      }
    __syncthreads();
    ushort* eT = (y == 1) ? eTt0 : (y == 2) ? eTt1 : eTt2;
    const int bb_ = blockIdx.x >> 5, kstep = blockIdx.x & 31;
    uint4* dst = (uint4*)(eT + ((size_t)(bb_ * 32 + kstep)) * 8192);
    const uint4* src = (const uint4*)tr;
#pragma unroll
    for (int ii = 0; ii < 4; ++ii) dst[ii * 256 + t] = src[ii * 256 + t];
  }
}

// ---------------------------------------------------------------------------
// Masked mean on packed bits + tiled eT (unchanged structure; A-read follows
// the new row-major pk tile layout).
__global__ __launch_bounds__(256, 3) void k_mm(
    const uchar* __restrict__ pk, const float* __restrict__ invdeg,
    const ushort* __restrict__ B0p, const ushort* __restrict__ B1p,
    const ushort* __restrict__ B2p,
    ushort* __restrict__ P, ushort* __restrict__ S, ushort* __restrict__ T) {
  __shared__ __align__(16) char smem[49152];  // A bits @0 (16K), B bufs @16K/32K
  const int t = threadIdx.x;
  const int g = blockIdx.x;
  const int X = g & 7, seq = g >> 3;
  const int pl = seq >> 5, mtile = seq & 31;
  const int panel = pl * 8 + X;
  const int b = panel / 3, mid = panel - b * 3;
  const ushort* Bt = (mid == 0) ? B0p : (mid == 1) ? B1p : B2p;
  ushort* outp = (mid == 0) ? P : (mid == 1) ? S : T;
  const uchar* pkT = pk + ((((size_t)(mid * 8 + b)) * 32 + mtile)) * 16384;
  const uchar* BtT = (const uchar*)Bt + ((size_t)b * 32) * 16384;
  const int lane = t & 63, wave = t >> 6;
  const int m0w = (wave >> 1) * 32, n0w = (wave & 1) * 64;
  const int quad = lane >> 4, lr = lane & 15;
  f32x4 acc[2][4] = {};

#define STG_A()                                                               \
  {                                                                           \
    _Pragma("unroll") for (int ii = 0; ii < 4; ++ii)                          \
        __builtin_amdgcn_global_load_lds(                                     \
            (const __attribute__((address_space(1))) uint*)(pkT +             \
                wave * 4096 + ii * 1024 + lane * 16),                         \
            (__attribute__((address_space(3))) uint*)(smem + wave * 4096 +    \
                ii * 1024 + lane * 16),                                       \
            16, 0, 0);                                                        \
  }
#define STG_B(BUF, STEP)                                                      \
  {                                                                           \
    _Pragma("unroll") for (int ii = 0; ii < 4; ++ii)                          \
        __builtin_amdgcn_global_load_lds(                                     \
            (const __attribute__((address_space(1))) uint*)(BtT +             \
                (size_t)(STEP) * 16384 + wave * 4096 + ii * 1024 + lane * 16),\
            (__attribute__((address_space(3))) uint*)(smem + 16384 +          \
                (BUF) * 16384 + wave * 4096 + ii * 1024 + lane * 16),         \
            16, 0, 0);                                                        \
  }
#define CPT(SS, BUF)                                                          \
  {                                                                           \
    const char* Ab = smem;                                                    \
    const char* Bb = smem + 16384 + (BUF) * 16384;                            \
    uint2 wa = *(const uint2*)(Ab + (m0w + lr) * 256 + (((SS) ^ lr) << 3));   \
    uint2 wb = *(const uint2*)(Ab + (m0w + 16 + lr) * 256 +                   \
                               (((SS) ^ (16 + lr)) << 3));                    \
    _Pragma("unroll") for (int kc = 0; kc < 2; ++kc) {                        \
      uint wax = kc ? wa.y : wa.x;                                            \
      uint wbx = kc ? wb.y : wb.x;                                            \
      bf16x8 a0 = bits2bf((wax >> (quad * 8)) & 0xFFu);                       \
      bf16x8 a1 = bits2bf((wbx >> (quad * 8)) & 0xFFu);                       \
      const int sl = (((kc * 4 + quad) ^ (lr & 7)) << 4);                     \
      bf16x8 b0 = *(const bf16x8*)(Bb + (n0w + lr) * 128 + sl);               \
      bf16x8 b1 = *(const bf16x8*)(Bb + (n0w + 16 + lr) * 128 + sl);          \
      bf16x8 b2 = *(const bf16x8*)(Bb + (n0w + 32 + lr) * 128 + sl);          \
      bf16x8 b3 = *(const bf16x8*)(Bb + (n0w + 48 + lr) * 128 + sl);          \
      __builtin_amdgcn_s_setprio(1);                                          \
      acc[0][0] = __builtin_amdgcn_mfma_f32_16x16x32_bf16(a0, b0, acc[0][0], 0, 0, 0); \
      acc[1][0] = __builtin_amdgcn_mfma_f32_16x16x32_bf16(a1, b0, acc[1][0], 0, 0, 0); \
      acc[0][1] = __builtin_amdgcn_mfma_f32_16x16x32_bf16(a0, b1, acc[0][1], 0, 0, 0); \
      acc[1][1] = __builtin_amdgcn_mfma_f32_16x16x32_bf16(a1, b1, acc[1][1], 0, 0, 0); \
      acc[0][2] = __builtin_amdgcn_mfma_f32_16x16x32_bf16(a0, b2, acc[0][2], 0, 0, 0); \
      acc[1][2] = __builtin_amdgcn_mfma_f32_16x16x32_bf16(a1, b2, acc[1][2], 0, 0, 0); \
      acc[0][3] = __builtin_amdgcn_mfma_f32_16x16x32_bf16(a0, b3, acc[0][3], 0, 0, 0); \
      acc[1][3] = __builtin_amdgcn_mfma_f32_16x16x32_bf16(a1, b3, acc[1][3], 0, 0, 0); \
      __builtin_amdgcn_s_setprio(0);                                          \
    }                                                                         \
  }

  STG_A()
  STG_B(0, 0)
  STG_B(1, 1)
  for (int s = 0; s < 32; ++s) {
    if (s < 31) asm volatile("s_waitcnt vmcnt(4)" ::: "memory");
    else        asm volatile("s_waitcnt vmcnt(0)" ::: "memory");
    __builtin_amdgcn_s_barrier();
    __builtin_amdgcn_sched_barrier(0);
    CPT(s, s & 1)
    asm volatile("" ::: "memory");
    __builtin_amdgcn_s_barrier();
    if (s < 30) STG_B(s & 1, s + 2)
  }
  __builtin_amdgcn_sched_barrier(0);
#undef CPT
#undef STG_B
#undef STG_A

  const size_t rowbase = (size_t)b * 2048 + mtile * 64;
  const float* inv = invdeg + ((size_t)(mid * 8 + b)) * 2048 + mtile * 64;
#pragma unroll
  for (int i = 0; i < 2; ++i)
#pragma unroll
    for (int r = 0; r < 4; ++r) {
      int ml = m0w + i * 16 + quad * 4 + r;
      float iv = inv[ml];
#pragma unroll
      for (int j = 0; j < 4; ++j) {
        int n = n0w + j * 16 + lr;
        outp[(rowbase + ml) * 128 + n] = f2bf(acc[i][j][r] * iv);
      }
    }
}

// ---------------------------------------------------------------------------
__device__ __forceinline__ void gemm_body(
    const ushort* __restrict__ A0, const ushort* __restrict__ A1,
    const ushort* __restrict__ A2, const ushort* __restrict__ Bsrc,
    int bstride, int K, const float* __restrict__ bias,
    void* __restrict__ out, int out_f32, int gm0, int t) {
  const int lane = t & 63, wave = t >> 6;
  const int m0w = (wave >> 1) * 32, n0w = (wave & 1) * 64;
  const int quad = lane >> 4, lr = lane & 15;
  const ushort* bbase = Bsrc + (size_t)(n0w + lr) * bstride + quad * 8;
  f32x4 acc[2][4] = {};
  for (int k0 = 0; k0 < K; k0 += 64) {
    const int seg = k0 >> 7;
    const ushort* Ap = (seg == 0) ? A0 : (seg == 1) ? A1 : A2;
    const int ko = k0 & 127;
    const ushort* a0p = Ap + (size_t)(gm0 + m0w + lr) * 128 + ko + quad * 8;
    const ushort* a1p = a0p + 16 * 128;
#pragma unroll
    for (int kc = 0; kc < 2; ++kc) {
      bf16x8 av0 = *(const bf16x8*)(a0p + kc * 32);
      bf16x8 av1 = *(const bf16x8*)(a1p + kc * 32);
      bf16x8 b0 = *(const bf16x8*)(bbase + k0 + kc * 32);
      bf16x8 b1 = *(const bf16x8*)(bbase + (size_t)16 * bstride + k0 + kc * 32);
      bf16x8 b2 = *(const bf16x8*)(bbase + (size_t)32 * bstride + k0 + kc * 32);
      bf16x8 b3 = *(const bf16x8*)(bbase + (size_t)48 * bstride + k0 + kc * 32);
      acc[0][0] = __builtin_amdgcn_mfma_f32_16x16x32_bf16(av0, b0, acc[0][0], 0, 0, 0);
      acc[1][0] = __builtin_amdgcn_mfma_f32_16x16x32_bf16(av1, b0, acc[1][0], 0, 0, 0);
      acc[0][1] = __builtin_amdgcn_mfma_f32_16x16x32_bf16(av0, b1, acc[0][1], 0, 0, 0);
      acc[1][1] = __builtin_amdgcn_mfma_f32_16x16x32_bf16(av1, b1, acc[1][1], 0, 0, 0);
      acc[0][2] = __builtin_amdgcn_mfma_f32_16x16x32_bf16(av0, b2, acc[0][2], 0, 0, 0);
      acc[1][2] = __builtin_amdgcn_mfma_f32_16x16x32_bf16(av1, b2, acc[1][2], 0, 0, 0);
      acc[0][3] = __builtin_amdgcn_mfma_f32_16x16x32_bf16(av0, b3, acc[0][3], 0, 0, 0);
      acc[1][3] = __builtin_amdgcn_mfma_f32_16x16x32_bf16(av1, b3, acc[1][3], 0, 0, 0);
    }
  }
#pragma unroll
  for (int i = 0; i < 2; ++i)
#pragma unroll
    for (int j = 0; j < 4; ++j) {
      const int n = n0w + j * 16 + lr;
      const float bb = bias[n];
      const int mb = gm0 + m0w + i * 16 + quad * 4;
      if (out_f32) {
#pragma unroll
        for (int r = 0; r < 4; ++r)
          ((float*)out)[(size_t)(mb + r) * 128 + n] = acc[i][j][r] + bb;
      } else {
#pragma unroll
        for (int r = 0; r < 4; ++r)
          ((ushort*)out)[(size_t)(mb + r) * 128 + n] = f2bf(acc[i][j][r] + bb);
      }
    }
}

__global__ __launch_bounds__(256) void k_xy(
    const ushort* __restrict__ P, const ushort* __restrict__ origin,
    const ushort* __restrict__ S, const ushort* __restrict__ T,
    const ushort* __restrict__ WTs, const ushort* __restrict__ WTm,
    const float* __restrict__ bs, const float* __restrict__ bm,
    ushort* __restrict__ X, ushort* __restrict__ Y) {
  const int gm0 = blockIdx.x * 64;
  if (blockIdx.y == 0)
    gemm_body(P, origin, S, WTs, 384, 384, bs, X, 0, gm0, threadIdx.x);
  else
    gemm_body(origin, T, nullptr, WTm, 256, 256, bm, Y, 0, gm0, threadIdx.x);
}

__global__ __launch_bounds__(256) void k_mix(
    const ushort* __restrict__ X, const ushort* __restrict__ Y,
    const ushort* __restrict__ WTx, const float* __restrict__ bx,
    float* __restrict__ out) {
  gemm_body(X, Y, nullptr, WTx, 256, 256, bx, out, 1, blockIdx.x * 64, threadIdx.x);
}

// ---------------------------------------------------------------------------
extern "C" void kernel_launch(void* const* d_in, const int* in_sizes, int n_in,
                              void* d_out, int out_size, void* d_ws,
                              size_t ws_size, hipStream_t stream) {
  const float* features = (const float*)d_in[0];
  const void* pred = d_in[1];
  const void* succ = d_in[2];
  const void* same = d_in[3];
  const float* W_enc = (const float*)d_in[4];
  const float* b_enc = (const float*)d_in[5];
  const float* W_space = (const float*)d_in[6];
  const float* b_space = (const float*)d_in[7];
  const float* W_same = (const float*)d_in[8];
  const float* b_same = (const float*)d_in[9];
  const float* W_mix = (const float*)d_in[10];
  const float* b_mix = (const float*)d_in[11];

  const size_t M = 16384;
  ushort* w = (ushort*)d_ws;
  ushort* WT_enc = w;   w += 512 * 128;
  ushort* WT_space = w; w += 128 * 384;
  ushort* WT_same = w;  w += 128 * 256;
  ushort* WT_mix = w;   w += 128 * 256;
  ushort* origin = w;   w += M * 128;
  ushort* eTt0 = w;     w += M * 128;
  ushort* eTt1 = w;     w += M * 128;
  ushort* eTt2 = w;     w += M * 128;
  ushort* P = w;        w += M * 128;
  ushort* S = w;        w += M * 128;
  ushort* T = w;        w += M * 128;
  // pk = 3*8*2048*2048 bits = 12,582,912 B = 6,291,456 ushorts.
  // X,Y alias pk (pk dies after k_mm; X/Y born at k_xy).
  uchar* pk = (uchar*)w;
  ushort* X = w;
  ushort* Y = w + M * 128;
  w += 6291456;
  float* invdeg = (float*)w;  w += 98304;
  int* esz = (int*)w;

  k_detect<<<1, 256, 0, stream>>>((const uint4*)pred, esz);
  k_front<<<2240, 256, 0, stream>>>(pred, succ, same, pk, invdeg, esz,
                                    W_enc, W_space, W_same, W_mix,
                                    WT_enc, WT_space, WT_same, WT_mix);
  k_enc<<<dim3(256, 4), 256, 0, stream>>>(features, WT_enc, b_enc,
                                          origin, eTt0, eTt1, eTt2);
  k_mm<<<768, 256, 0, stream>>>(pk, invdeg, eTt0, eTt1, eTt2, P, S, T);
  k_xy<<<dim3(256, 2), 256, 0, stream>>>(P, origin, S, T, WT_space, WT_same,
                                         b_space, b_same, X, Y);
  k_mix<<<256, 256, 0, stream>>>(X, Y, WT_mix, b_mix, (float*)d_out);
}